// Round 7
// baseline (4092.202 us; speedup 1.0000x reference)
//
#include <hip/hip_runtime.h>
#include <cstdint>

// binary_disordered_RNNwavefunction: 128-step 2-layer GRU + MLP + softmax +
// threefry categorical sampling, B=8192, H=128, I=2.
//
// R7 (vs R6, which measured 35% idle from serial combine phases + 6 barriers):
// wave w owns jt tiles {w, w+8, w+16} = r,z,n gate columns for the SAME cols
// and batch rows -> GRU combines fused INTO the GEMM waves:
//   P1: GRU0 3 tiles (A=h1_prev) + INLINE GRU0 combine (gates never touch
//       LDS) -> h1 frags; GH1a 3 tiles (A=h2_prev) -> gates CARRIED IN REGS
//       across the barrier. P2: GH1b 3 tiles (A=h1_new) + inline GRU1 + cos.
//   P3: HDN. P4: OUT.  6 barriers -> 4; S0/S1 gate storage eliminated.
// h1 frag buffers ping-pong by step parity (P1 reads prev h1 while writing new).
//
// Numerics (verified R4-R6, absmax 0.0039 = comparison floor): split-f16
// a = a1 + a2s/4096; 3 MFMAs/tile; dropped A2sB2s ~3e-8; bias association
// changes are 1e-7 class (flip-safe). RNG: modern JAX threefry_partitionable.
// R2: few blocks, lockstep L2. R5: AI per B-load ~ BTM. R6: dbuf B prefetch.

namespace {

constexpr int NSTEPS = 128;
constexpr int HDIM = 128;
constexpr int G3H = 384;

constexpr int BTM = 32;        // batch rows per block
constexpr int THM = 512;       // threads (8 waves)

// fallback (R3) config
constexpr int BT = 16;
constexpr int THREADS = 256;
constexpr int HP = 132;
constexpr int SP = 516;

typedef _Float16 half8 __attribute__((ext_vector_type(8)));
typedef float f32x4 __attribute__((ext_vector_type(4)));

constexpr float LO_SCALE = 4096.0f;
constexpr float LO_INV = 2.44140625e-4f;   // 1/4096
constexpr float F16_MIN_NORM = 6.104e-5f;

__device__ __forceinline__ void split_f16(float x, _Float16& a1, _Float16& a2s) {
  _Float16 h = (fabsf(x) < F16_MIN_NORM) ? (_Float16)0.0f : (_Float16)x;
  a1 = h;
  a2s = (_Float16)((x - (float)h) * LO_SCALE);
}

__device__ __forceinline__ void tf2x32(uint32_t k0, uint32_t k1,
                                       uint32_t x0, uint32_t x1,
                                       uint32_t& o0, uint32_t& o1) {
  const uint32_t ks2 = k0 ^ k1 ^ 0x1BD11BDAu;
  uint32_t v0 = x0 + k0;
  uint32_t v1 = x1 + k1;
  const uint32_t ks[3] = {k0, k1, ks2};
  const uint32_t rotA[4] = {13u, 15u, 26u, 6u};
  const uint32_t rotB[4] = {17u, 29u, 16u, 24u};
#pragma unroll
  for (int i = 0; i < 5; ++i) {
#pragma unroll
    for (int j = 0; j < 4; ++j) {
      const uint32_t r = (i & 1) ? rotB[j] : rotA[j];
      v0 += v1;
      v1 = (v1 << r) | (v1 >> (32u - r));
      v1 ^= v0;
    }
    v0 += ks[(i + 1) % 3];
    v1 += ks[(i + 2) % 3] + (uint32_t)(i + 1);
  }
  o0 = v0;
  o1 = v1;
}

__device__ __forceinline__ float u01_from_bits(uint32_t bits) {
  const float tiny = 1.1754943508222875e-38f;
  float f = __uint_as_float((bits >> 9) | 0x3F800000u) - 1.0f;
  float u = f * (1.0f - tiny) + tiny;
  return fmaxf(tiny, u);
}

__device__ __forceinline__ float sigmoidf(float x) {
  return 1.0f / (1.0f + expf(-x));
}

__device__ __forceinline__ float dot4(const float4 a, const float4 b, float c) {
  c = fmaf(a.x, b.x, c);
  c = fmaf(a.y, b.y, c);
  c = fmaf(a.z, b.z, c);
  c = fmaf(a.w, b.w, c);
  return c;
}

__device__ __forceinline__ void load_Afrag(const _Float16* arr, int lane,
                                           half8 (&A)[2][4]) {
#pragma unroll
  for (int mt = 0; mt < 2; ++mt)
#pragma unroll
    for (int kt = 0; kt < 4; ++kt)
      A[mt][kt] = *(const half8*)(arr + mt * 2048 + (kt * 64 + lane) * 8);
}

__device__ __forceinline__ void load_B(const _Float16* __restrict__ B1,
                                       const _Float16* __restrict__ B2,
                                       int jt, int lane,
                                       half8 (&b1)[4], half8 (&b2)[4]) {
#pragma unroll
  for (int kt = 0; kt < 4; ++kt) {
    const size_t o = ((size_t)(jt * 4 + kt) * 64 + lane) * 8;
    b1[kt] = *(const half8*)(B1 + o);
    b2[kt] = *(const half8*)(B2 + o);
  }
}

__device__ __forceinline__ void mfma_regs(const half8 (&A1)[2][4],
                                          const half8 (&A2)[2][4],
                                          const half8 (&b1)[4],
                                          const half8 (&b2)[4],
                                          f32x4 (&c1)[2], f32x4 (&c2)[2]) {
#pragma unroll
  for (int kt = 0; kt < 4; ++kt)
#pragma unroll
    for (int mt = 0; mt < 2; ++mt) {
      c1[mt] = __builtin_amdgcn_mfma_f32_16x16x32_f16(A1[mt][kt], b1[kt], c1[mt], 0, 0, 0);
      c2[mt] = __builtin_amdgcn_mfma_f32_16x16x32_f16(A1[mt][kt], b2[kt], c2[mt], 0, 0, 0);
      c2[mt] = __builtin_amdgcn_mfma_f32_16x16x32_f16(A2[mt][kt], b1[kt], c2[mt], 0, 0, 0);
    }
}

__device__ __forceinline__ void zacc(f32x4 (&c)[2]) {
  c[0] = f32x4{0.f, 0.f, 0.f, 0.f};
  c[1] = f32x4{0.f, 0.f, 0.f, 0.f};
}

// g[mt][k] = bias + (c1 + c2/4096)
__device__ __forceinline__ void fold2(f32x4 (&g)[2], const f32x4 (&c1)[2],
                                      const f32x4 (&c2)[2], float bias) {
#pragma unroll
  for (int mt = 0; mt < 2; ++mt)
#pragma unroll
    for (int k = 0; k < 4; ++k)
      g[mt][k] = bias + fmaf(c2[mt][k], LO_INV, c1[mt][k]);
}

}  // namespace

// ---------------------------------------------------------------------------
// Preprocess: fp32 W[n][JT*16][128] -> frag-layout split-f16 arrays (as R4)
// ---------------------------------------------------------------------------
extern "C" __global__ __launch_bounds__(256)
void preprocess_split_kernel(const float* __restrict__ src,
                             _Float16* __restrict__ d1,
                             _Float16* __restrict__ d2,
                             int total, int JT) {
  const int idx = blockIdx.x * 256 + threadIdx.x;
  if (idx >= total) return;
  const int lane = idx & 63;
  const int kt = (idx >> 6) & 3;
  const int rest = idx >> 8;
  const int jt = rest % JT;
  const int nstep = rest / JT;

  const int j = jt * 16 + (lane & 15);
  const int k0 = kt * 32 + ((lane >> 4) << 3);
  const float* p = src + ((size_t)nstep * (JT * 16) + j) * 128 + k0;
  const float4 w0 = *(const float4*)p;
  const float4 w1 = *(const float4*)(p + 4);
  const float xs[8] = {w0.x, w0.y, w0.z, w0.w, w1.x, w1.y, w1.z, w1.w};

  half8 o1, o2;
#pragma unroll
  for (int t = 0; t < 8; ++t) {
    _Float16 a1, a2s;
    split_f16(xs[t], a1, a2s);
    o1[t] = a1;
    o2[t] = a2s;
  }
  *(half8*)(d1 + (size_t)idx * 8) = o1;
  *(half8*)(d2 + (size_t)idx * 8) = o2;
}

// ---------------------------------------------------------------------------
// Main MFMA kernel: BT=32, 512 threads, 1 block/CU, fused combines
// ---------------------------------------------------------------------------
extern "C" __global__ __launch_bounds__(512, 2)
void rnn_wavefn_mfma_kernel(const float* __restrict__ inputs,
                            const float* __restrict__ Wih0,
                            const float* __restrict__ bih0,
                            const float* __restrict__ bhh0,
                            const float* __restrict__ bih1,
                            const float* __restrict__ bhh1,
                            const float* __restrict__ b1,
                            const float* __restrict__ W2,
                            const float* __restrict__ b2,
                            const _Float16* __restrict__ Whh0_1,
                            const _Float16* __restrict__ Whh0_2,
                            const _Float16* __restrict__ Wih1_1,
                            const _Float16* __restrict__ Wih1_2,
                            const _Float16* __restrict__ Whh1_1,
                            const _Float16* __restrict__ Whh1_2,
                            const _Float16* __restrict__ W1_1,
                            const _Float16* __restrict__ W1_2,
                            float* __restrict__ out) {
  __shared__ _Float16 h1Aa1[4096], h1Aa2[4096];   // h1 frag ping
  __shared__ _Float16 h1Ab1[4096], h1Ab2[4096];   // h1 frag pong
  __shared__ _Float16 h2A1[4096], h2A2[4096];
  __shared__ _Float16 csA1[4096], csA2[4096];
  __shared__ float Shdn[BTM][132];
  __shared__ float xin[BTM][2];

  const int tid = threadIdx.x;
  const int b0 = blockIdx.x * BTM;
  const int wv = tid >> 6;        // 0..7
  const int lane = tid & 63;
  const int lm = lane & 15;
  const int m0 = (lane >> 4) * 4;
  const int col0 = wv * 16 + lm;  // this thread's gate column (r offset)
  // A-frag write base for d=col0 (b16 element index, add mt*2048 + b_in16*8)
  const int fw = (((col0 >> 5) * 64 + ((col0 >> 3) & 3) * 16) * 8) + (col0 & 7);

  float h1r[8], h2r[8];           // j = mt*4 + q  ->  b = mt*16 + m0 + q
#pragma unroll
  for (int i = 0; i < 8; ++i) { h1r[i] = 0.0f; h2r[i] = 0.0f; }
  for (int i = tid; i < 4096; i += THM) {
    h1Aa1[i] = (_Float16)0.0f; h1Aa2[i] = (_Float16)0.0f;
    h1Ab1[i] = (_Float16)0.0f; h1Ab2[i] = (_Float16)0.0f;
    h2A1[i] = (_Float16)0.0f;  h2A2[i] = (_Float16)0.0f;
  }
  if (tid < BTM * 2) {
    xin[tid >> 1][tid & 1] = inputs[(b0 + (tid >> 1)) * 2 + (tid & 1)];
  }
  __syncthreads();

  for (int n = 0; n < NSTEPS; ++n) {
    const float* __restrict__ Wih0n = Wih0 + (size_t)n * G3H * 2;
    const float* __restrict__ bih0n = bih0 + (size_t)n * G3H;
    const float* __restrict__ bhh0n = bhh0 + (size_t)n * G3H;
    const float* __restrict__ bih1n = bih1 + (size_t)n * G3H;
    const float* __restrict__ bhh1n = bhh1 + (size_t)n * G3H;
    const float* __restrict__ b1n = b1 + (size_t)n * HDIM;
    const float* __restrict__ W2n = W2 + (size_t)n * 2 * HDIM;
    const float* __restrict__ b2n = b2 + (size_t)n * 2;
    const size_t fo3 = (size_t)n * 49152;
    const size_t fo1 = (size_t)n * 16384;

    // h1 frag ping-pong: write buffer (this step), read buffer (prev step)
    _Float16* const h1W1 = (n & 1) ? h1Ab1 : h1Aa1;
    _Float16* const h1W2 = (n & 1) ? h1Ab2 : h1Aa2;
    const _Float16* const h1R1 = (n & 1) ? h1Aa1 : h1Ab1;
    const _Float16* const h1R2 = (n & 1) ? h1Aa2 : h1Ab2;

    f32x4 g1r[2], g1z[2], g1n[2];   // GH1a gates, carried P1 -> P2

    // ---------- P1: GRU0 (3 tiles + inline combine) + GH1a (3 tiles -> regs)
    {
      const float wr0 = Wih0n[col0 * 2],           wr1 = Wih0n[col0 * 2 + 1];
      const float wz0 = Wih0n[(col0 + 128) * 2],   wz1 = Wih0n[(col0 + 128) * 2 + 1];
      const float wn0 = Wih0n[(col0 + 256) * 2],   wn1 = Wih0n[(col0 + 256) * 2 + 1];
      const float br = bih0n[col0];
      const float bz = bih0n[col0 + 128];
      const float bn = bih0n[col0 + 256];

      half8 A1[2][4], A2[2][4];
      load_Afrag(h1R1, lane, A1);
      load_Afrag(h1R2, lane, A2);
      const _Float16* B0h = Whh0_1 + fo3;
      const _Float16* B0l = Whh0_2 + fo3;
      const _Float16* B1h_ = Whh1_1 + fo3;
      const _Float16* B1l_ = Whh1_2 + fo3;
      half8 Pb1[2][4], Pb2[2][4];
      load_B(B0h, B0l, wv, lane, Pb1[0], Pb2[0]);

      f32x4 c1[2], c2[2], g0r[2], g0z[2], g0n[2];
      // t0: GRU0 r
      load_B(B0h, B0l, wv + 8, lane, Pb1[1], Pb2[1]);
      zacc(c1); zacc(c2);
      mfma_regs(A1, A2, Pb1[0], Pb2[0], c1, c2);
      fold2(g0r, c1, c2, bhh0n[col0]);
      // t1: GRU0 z
      load_B(B0h, B0l, wv + 16, lane, Pb1[0], Pb2[0]);
      zacc(c1); zacc(c2);
      mfma_regs(A1, A2, Pb1[1], Pb2[1], c1, c2);
      fold2(g0z, c1, c2, bhh0n[col0 + 128]);
      // t2: GRU0 n  (prefetch first GH1a tile)
      load_B(B1h_, B1l_, wv, lane, Pb1[1], Pb2[1]);
      zacc(c1); zacc(c2);
      mfma_regs(A1, A2, Pb1[0], Pb2[0], c1, c2);
      fold2(g0n, c1, c2, bhh0n[col0 + 256]);

      // inline GRU0 combine -> h1 regs + frag write (overlaps GH1a loads)
#pragma unroll
      for (int j = 0; j < 8; ++j) {
        const int mt = j >> 2, q = j & 3;
        const int b = mt * 16 + m0 + q;
        const float x0 = xin[b][0], x1 = xin[b][1];
        const float gir = fmaf(wr0, x0, fmaf(wr1, x1, br));
        const float giz = fmaf(wz0, x0, fmaf(wz1, x1, bz));
        const float ginn = fmaf(wn0, x0, fmaf(wn1, x1, bn));
        const float rg = sigmoidf(gir + g0r[mt][q]);
        const float zg = sigmoidf(giz + g0z[mt][q]);
        const float ng = tanhf(ginn + rg * g0n[mt][q]);
        const float h1n = (1.0f - zg) * ng + zg * h1r[j];
        h1r[j] = h1n;
        _Float16 a1h, a2h;
        split_f16(h1n, a1h, a2h);
        const int off = fw + mt * 2048 + (m0 + q) * 8;
        h1W1[off] = a1h;
        h1W2[off] = a2h;
      }

      // switch A to h2 (prev step)
      load_Afrag(h2A1, lane, A1);
      load_Afrag(h2A2, lane, A2);
      // t3: GH1a r
      load_B(B1h_, B1l_, wv + 8, lane, Pb1[0], Pb2[0]);
      zacc(c1); zacc(c2);
      mfma_regs(A1, A2, Pb1[1], Pb2[1], c1, c2);
      fold2(g1r, c1, c2, bhh1n[col0]);
      // t4: GH1a z
      load_B(B1h_, B1l_, wv + 16, lane, Pb1[1], Pb2[1]);
      zacc(c1); zacc(c2);
      mfma_regs(A1, A2, Pb1[0], Pb2[0], c1, c2);
      fold2(g1z, c1, c2, bhh1n[col0 + 128]);
      // t5: GH1a n
      zacc(c1); zacc(c2);
      mfma_regs(A1, A2, Pb1[1], Pb2[1], c1, c2);
      fold2(g1n, c1, c2, bhh1n[col0 + 256]);
    }
    __syncthreads();

    // ---------- P2: GH1b (Wih1 . h1new, 3 tiles) + inline GRU1 + cos
    {
      half8 A1[2][4], A2[2][4];
      load_Afrag(h1W1, lane, A1);
      load_Afrag(h1W2, lane, A2);
      const _Float16* Bh = Wih1_1 + fo3;
      const _Float16* Bl = Wih1_2 + fo3;
      half8 Pb1[2][4], Pb2[2][4];
      load_B(Bh, Bl, wv, lane, Pb1[0], Pb2[0]);
      f32x4 c1[2], c2[2], rr[2], zz[2], gg[2];
      // t0: gi1 r -> r gate
      load_B(Bh, Bl, wv + 8, lane, Pb1[1], Pb2[1]);
      zacc(c1); zacc(c2);
      mfma_regs(A1, A2, Pb1[0], Pb2[0], c1, c2);
      {
        const float bias = bih1n[col0];
#pragma unroll
        for (int mt = 0; mt < 2; ++mt)
#pragma unroll
          for (int k = 0; k < 4; ++k)
            rr[mt][k] = sigmoidf(bias + fmaf(c2[mt][k], LO_INV, c1[mt][k]) + g1r[mt][k]);
      }
      // t1: gi1 z -> z gate
      load_B(Bh, Bl, wv + 16, lane, Pb1[0], Pb2[0]);
      zacc(c1); zacc(c2);
      mfma_regs(A1, A2, Pb1[1], Pb2[1], c1, c2);
      {
        const float bias = bih1n[col0 + 128];
#pragma unroll
        for (int mt = 0; mt < 2; ++mt)
#pragma unroll
          for (int k = 0; k < 4; ++k)
            zz[mt][k] = sigmoidf(bias + fmaf(c2[mt][k], LO_INV, c1[mt][k]) + g1z[mt][k]);
      }
      // t2: gi1 n
      zacc(c1); zacc(c2);
      mfma_regs(A1, A2, Pb1[0], Pb2[0], c1, c2);
      fold2(gg, c1, c2, bih1n[col0 + 256]);
      // inline GRU1 combine + cos; write h2/cos frags
#pragma unroll
      for (int j = 0; j < 8; ++j) {
        const int mt = j >> 2, q = j & 3;
        const float ng = tanhf(gg[mt][q] + rr[mt][q] * g1n[mt][q]);
        const float h2n = (1.0f - zz[mt][q]) * ng + zz[mt][q] * h2r[j];
        h2r[j] = h2n;
        const int off = fw + mt * 2048 + (m0 + q) * 8;
        _Float16 a1h, a2h;
        split_f16(h2n, a1h, a2h);
        h2A1[off] = a1h;
        h2A2[off] = a2h;
        const float cv = cosf(h2n) + 1e-10f;
        split_f16(cv, a1h, a2h);
        csA1[off] = a1h;
        csA2[off] = a2h;
      }
    }
    __syncthreads();

    // ---------- P3: HDN = relu(b1 + W1 . cos)
    {
      half8 A1[2][4], A2[2][4];
      load_Afrag(csA1, lane, A1);
      load_Afrag(csA2, lane, A2);
      half8 b1v[4], b2v[4];
      load_B(W1_1 + fo1, W1_2 + fo1, wv, lane, b1v, b2v);
      f32x4 c1[2], c2[2];
      zacc(c1); zacc(c2);
      mfma_regs(A1, A2, b1v, b2v, c1, c2);
      const float bias = b1n[col0];
#pragma unroll
      for (int mt = 0; mt < 2; ++mt)
#pragma unroll
        for (int q = 0; q < 4; ++q)
          Shdn[mt * 16 + m0 + q][col0] =
              fmaxf(bias + fmaf(c2[mt][q], LO_INV, c1[mt][q]), 0.0f);
    }
    __syncthreads();

    // ---------- P4 OUT: logits, softmax+1e-10, store p, threefry-gumbel
    {
      const int ln = tid & 15;
      const int ob = tid >> 4;    // 0..31
      const int kb = ln * 8;
      float a0 = 0.0f, a1 = 0.0f;
#pragma unroll
      for (int k = 0; k < 8; ++k) {
        const float hd = Shdn[ob][kb + k];
        a0 = fmaf(W2n[kb + k], hd, a0);
        a1 = fmaf(W2n[HDIM + kb + k], hd, a1);
      }
#pragma unroll
      for (int off = 8; off >= 1; off >>= 1) {
        a0 += __shfl_xor(a0, off, 16);
        a1 += __shfl_xor(a1, off, 16);
      }
      if (ln == 0) {
        const float l0 = a0 + b2n[0];
        const float l1 = a1 + b2n[1];
        const float m = fmaxf(l0, l1);
        const float e0 = expf(l0 - m);
        const float e1 = expf(l1 - m);
        const float sum = e0 + e1;
        const float p0 = e0 / sum + 1e-10f;
        const float p1 = e1 / sum + 1e-10f;
        const int gb = b0 + ob;
        out[((size_t)gb * NSTEPS + n) * 2 + 0] = p0;
        out[((size_t)gb * NSTEPS + n) * 2 + 1] = p1;

        uint32_t k0n, k1n;
        tf2x32(0u, 42u, 0u, (uint32_t)n, k0n, k1n);
        uint32_t o0, o1;
        tf2x32(k0n, k1n, 0u, (uint32_t)(2 * gb), o0, o1);
        const float u0 = u01_from_bits(o0 ^ o1);
        tf2x32(k0n, k1n, 0u, (uint32_t)(2 * gb + 1), o0, o1);
        const float u1 = u01_from_bits(o0 ^ o1);
        const float g0 = -logf(-logf(u0));
        const float g1 = -logf(-logf(u1));
        const float z0 = logf(p0) + g0;
        const float z1 = logf(p1) + g1;
        const int smp = (z1 > z0) ? 1 : 0;
        xin[ob][0] = (smp == 0) ? 1.0f : 0.0f;
        xin[ob][1] = (smp == 1) ? 1.0f : 0.0f;
      }
    }
    __syncthreads();
  }
}

// ---------------------------------------------------------------------------
// Fallback: R3 fp32-VALU kernel (proven, 7.2 ms) — used if ws too small.
// ---------------------------------------------------------------------------
extern "C" __global__ __launch_bounds__(256, 2)
void rnn_wavefn_fp32_kernel(const float* __restrict__ inputs,
                            const float* __restrict__ Wih0,
                            const float* __restrict__ Whh0,
                            const float* __restrict__ bih0,
                            const float* __restrict__ bhh0,
                            const float* __restrict__ Wih1,
                            const float* __restrict__ Whh1,
                            const float* __restrict__ bih1,
                            const float* __restrict__ bhh1,
                            const float* __restrict__ W1,
                            const float* __restrict__ b1,
                            const float* __restrict__ W2,
                            const float* __restrict__ b2,
                            float* __restrict__ out) {
  __shared__ float h1[BT][HP];
  __shared__ float h2[BT][HP];
  __shared__ float S[BT][SP];
  __shared__ float xin[BT][2];

  const int tid = threadIdx.x;
  const int b0 = blockIdx.x * BT;
  const int tj = tid >> 2;
  const int tq = tid & 3;

  for (int i = tid; i < BT * HP; i += THREADS) {
    ((float*)h1)[i] = 0.0f;
    ((float*)h2)[i] = 0.0f;
  }
  if (tid < BT * 2) {
    xin[tid >> 1][tid & 1] = inputs[(b0 + (tid >> 1)) * 2 + (tid & 1)];
  }
  __syncthreads();

  for (int n = 0; n < NSTEPS; ++n) {
    const float* __restrict__ Wih0n = Wih0 + (size_t)n * G3H * 2;
    const float* __restrict__ Whh0n = Whh0 + (size_t)n * G3H * HDIM;
    const float* __restrict__ bih0n = bih0 + (size_t)n * G3H;
    const float* __restrict__ bhh0n = bhh0 + (size_t)n * G3H;
    const float* __restrict__ Wih1n = Wih1 + (size_t)n * G3H * HDIM;
    const float* __restrict__ Whh1n = Whh1 + (size_t)n * G3H * HDIM;
    const float* __restrict__ bih1n = bih1 + (size_t)n * G3H;
    const float* __restrict__ bhh1n = bhh1 + (size_t)n * G3H;
    const float* __restrict__ W1n = W1 + (size_t)n * HDIM * HDIM;
    const float* __restrict__ b1n = b1 + (size_t)n * HDIM;
    const float* __restrict__ W2n = W2 + (size_t)n * 2 * HDIM;
    const float* __restrict__ b2n = b2 + (size_t)n * 2;

    {
      float acc[6][4];
#pragma unroll
      for (int g = 0; g < 6; ++g) {
        const float bias = bhh0n[tj + g * 64];
#pragma unroll
        for (int i = 0; i < 4; ++i) acc[g][i] = bias;
      }
      for (int kk = 0; kk < HDIM; kk += 16) {
#pragma unroll
        for (int s = 0; s < 4; ++s) {
          const int k = kk + s * 4;
          float4 w[6];
#pragma unroll
          for (int g = 0; g < 6; ++g)
            w[g] = *(const float4*)(Whh0n + (size_t)(tj + g * 64) * HDIM + k);
#pragma unroll
          for (int i = 0; i < 4; ++i) {
            const float4 hv = *(const float4*)&h1[tq + 4 * i][k];
#pragma unroll
            for (int g = 0; g < 6; ++g) acc[g][i] = dot4(w[g], hv, acc[g][i]);
          }
        }
      }
#pragma unroll
      for (int g = 0; g < 6; ++g)
#pragma unroll
        for (int i = 0; i < 4; ++i) S[tq + 4 * i][tj + g * 64] = acc[g][i];
    }
    __syncthreads();

#pragma unroll
    for (int rep = 0; rep < (BT * HDIM) / THREADS; ++rep) {
      const int idx = tid + rep * THREADS;
      const int b = idx >> 7;
      const int d = idx & 127;
      const float x0 = xin[b][0];
      const float x1 = xin[b][1];
      const float gir = fmaf(Wih0n[d * 2 + 0], x0, fmaf(Wih0n[d * 2 + 1], x1, bih0n[d]));
      const float giz = fmaf(Wih0n[(d + 128) * 2 + 0], x0,
                             fmaf(Wih0n[(d + 128) * 2 + 1], x1, bih0n[d + 128]));
      const float gin = fmaf(Wih0n[(d + 256) * 2 + 0], x0,
                             fmaf(Wih0n[(d + 256) * 2 + 1], x1, bih0n[d + 256]));
      const float r = sigmoidf(gir + S[b][d]);
      const float z = sigmoidf(giz + S[b][d + 128]);
      const float nn = tanhf(gin + r * S[b][d + 256]);
      h1[b][d] = (1.0f - z) * nn + z * h1[b][d];
    }
    __syncthreads();

    {
      float acc[6][4];
#pragma unroll
      for (int g = 0; g < 6; ++g) {
        const float bias = bhh1n[tj + g * 64];
#pragma unroll
        for (int i = 0; i < 4; ++i) acc[g][i] = bias;
      }
      for (int kk = 0; kk < HDIM; kk += 16) {
#pragma unroll
        for (int s = 0; s < 4; ++s) {
          const int k = kk + s * 4;
          float4 w[6];
#pragma unroll
          for (int g = 0; g < 6; ++g)
            w[g] = *(const float4*)(Whh1n + (size_t)(tj + g * 64) * HDIM + k);
#pragma unroll
          for (int i = 0; i < 4; ++i) {
            const float4 hv = *(const float4*)&h2[tq + 4 * i][k];
#pragma unroll
            for (int g = 0; g < 6; ++g) acc[g][i] = dot4(w[g], hv, acc[g][i]);
          }
        }
      }
#pragma unroll
      for (int g = 0; g < 6; ++g)
#pragma unroll
        for (int i = 0; i < 4; ++i) S[tq + 4 * i][tj + g * 64] = acc[g][i];
    }

    {
      float acc[6][4];
#pragma unroll
      for (int g = 0; g < 6; ++g) {
        const float bias = bih1n[tj + g * 64];
#pragma unroll
        for (int i = 0; i < 4; ++i) acc[g][i] = bias;
      }
      for (int kk = 0; kk < HDIM; kk += 16) {
#pragma unroll
        for (int s = 0; s < 4; ++s) {
          const int k = kk + s * 4;
          float4 w[6];
#pragma unroll
          for (int g = 0; g < 6; ++g)
            w[g] = *(const float4*)(Wih1n + (size_t)(tj + g * 64) * HDIM + k);
#pragma unroll
          for (int i = 0; i < 4; ++i) {
            const float4 hv = *(const float4*)&h1[tq + 4 * i][k];
#pragma unroll
            for (int g = 0; g < 6; ++g) acc[g][i] = dot4(w[g], hv, acc[g][i]);
          }
        }
      }
#pragma unroll
      for (int g = 0; g < 6; ++g) {
        const int row = tj + g * 64;
#pragma unroll
        for (int i = 0; i < 4; ++i) {
          if (row < 256) S[tq + 4 * i][row] += acc[g][i];
          else           S[tq + 4 * i][row + 128] = acc[g][i];
        }
      }
    }
    __syncthreads();

#pragma unroll
    for (int rep = 0; rep < (BT * HDIM) / THREADS; ++rep) {
      const int idx = tid + rep * THREADS;
      const int b = idx >> 7;
      const int d = idx & 127;
      const float r = sigmoidf(S[b][d]);
      const float z = sigmoidf(S[b][d + 128]);
      const float nn = tanhf(S[b][d + 384] + r * S[b][d + 256]);
      const float h2n = (1.0f - z) * nn + z * h2[b][d];
      h2[b][d] = h2n;
      S[b][d] = cosf(h2n) + 1e-10f;
    }
    __syncthreads();

    {
      float acc[2][4];
#pragma unroll
      for (int g = 0; g < 2; ++g) {
        const float bias = b1n[tj + g * 64];
#pragma unroll
        for (int i = 0; i < 4; ++i) acc[g][i] = bias;
      }
      for (int kk = 0; kk < HDIM; kk += 16) {
#pragma unroll
        for (int s = 0; s < 4; ++s) {
          const int k = kk + s * 4;
          float4 w[2];
          w[0] = *(const float4*)(W1n + (size_t)(tj)*HDIM + k);
          w[1] = *(const float4*)(W1n + (size_t)(tj + 64) * HDIM + k);
#pragma unroll
          for (int i = 0; i < 4; ++i) {
            const float4 sv = *(const float4*)&S[tq + 4 * i][k];
            acc[0][i] = dot4(w[0], sv, acc[0][i]);
            acc[1][i] = dot4(w[1], sv, acc[1][i]);
          }
        }
      }
#pragma unroll
      for (int g = 0; g < 2; ++g)
#pragma unroll
        for (int i = 0; i < 4; ++i)
          S[tq + 4 * i][384 + tj + g * 64] = fmaxf(acc[g][i], 0.0f);
    }
    __syncthreads();

    {
      const int ln = tid & 15;
      const int b = tid >> 4;
      const int kb = ln * 8;
      float a0 = 0.0f, a1 = 0.0f;
#pragma unroll
      for (int k = 0; k < 8; ++k) {
        const float hd = S[b][384 + kb + k];
        a0 = fmaf(W2n[kb + k], hd, a0);
        a1 = fmaf(W2n[HDIM + kb + k], hd, a1);
      }
#pragma unroll
      for (int off = 8; off >= 1; off >>= 1) {
        a0 += __shfl_xor(a0, off, 16);
        a1 += __shfl_xor(a1, off, 16);
      }
      if (ln == 0) {
        const float l0 = a0 + b2n[0];
        const float l1 = a1 + b2n[1];
        const float m = fmaxf(l0, l1);
        const float e0 = expf(l0 - m);
        const float e1 = expf(l1 - m);
        const float sum = e0 + e1;
        const float p0 = e0 / sum + 1e-10f;
        const float p1 = e1 / sum + 1e-10f;
        const int gb = b0 + b;
        out[((size_t)gb * NSTEPS + n) * 2 + 0] = p0;
        out[((size_t)gb * NSTEPS + n) * 2 + 1] = p1;

        uint32_t k0n, k1n;
        tf2x32(0u, 42u, 0u, (uint32_t)n, k0n, k1n);
        uint32_t o0, o1;
        tf2x32(k0n, k1n, 0u, (uint32_t)(2 * gb), o0, o1);
        const float u0 = u01_from_bits(o0 ^ o1);
        tf2x32(k0n, k1n, 0u, (uint32_t)(2 * gb + 1), o0, o1);
        const float u1 = u01_from_bits(o0 ^ o1);
        const float g0 = -logf(-logf(u0));
        const float g1 = -logf(-logf(u1));
        const float z0 = logf(p0) + g0;
        const float z1 = logf(p1) + g1;
        const int smp = (z1 > z0) ? 1 : 0;
        xin[b][0] = (smp == 0) ? 1.0f : 0.0f;
        xin[b][1] = (smp == 1) ? 1.0f : 0.0f;
      }
    }
    __syncthreads();
  }
}

extern "C" void kernel_launch(void* const* d_in, const int* in_sizes, int n_in,
                              void* d_out, int out_size, void* d_ws, size_t ws_size,
                              hipStream_t stream) {
  (void)in_sizes; (void)n_in; (void)out_size;
  const float* inputs = (const float*)d_in[0];
  const float* Wih0 = (const float*)d_in[1];
  const float* Whh0 = (const float*)d_in[2];
  const float* bih0 = (const float*)d_in[3];
  const float* bhh0 = (const float*)d_in[4];
  const float* Wih1 = (const float*)d_in[5];
  const float* Whh1 = (const float*)d_in[6];
  const float* bih1 = (const float*)d_in[7];
  const float* bhh1 = (const float*)d_in[8];
  const float* W1 = (const float*)d_in[9];
  const float* b1 = (const float*)d_in[10];
  const float* W2 = (const float*)d_in[11];
  const float* b2 = (const float*)d_in[12];
  float* out = (float*)d_out;

  constexpr size_t EB = 6291456;        // 128*24*4*64*8
  constexpr size_t EW1 = 2097152;       // 128*8*4*64*8
  constexpr size_t WS_NEEDED = (6 * EB + 2 * EW1) * sizeof(_Float16);

  if (ws_size >= WS_NEEDED) {
    _Float16* w = (_Float16*)d_ws;
    _Float16* Whh0_1 = w;
    _Float16* Whh0_2 = w + EB;
    _Float16* Wih1_1 = w + 2 * EB;
    _Float16* Wih1_2 = w + 3 * EB;
    _Float16* Whh1_1 = w + 4 * EB;
    _Float16* Whh1_2 = w + 5 * EB;
    _Float16* W1_1 = w + 6 * EB;
    _Float16* W1_2 = w + 6 * EB + EW1;

    hipLaunchKernelGGL(preprocess_split_kernel, dim3(3072), dim3(256), 0, stream,
                       Whh0, Whh0_1, Whh0_2, 786432, 24);
    hipLaunchKernelGGL(preprocess_split_kernel, dim3(3072), dim3(256), 0, stream,
                       Wih1, Wih1_1, Wih1_2, 786432, 24);
    hipLaunchKernelGGL(preprocess_split_kernel, dim3(3072), dim3(256), 0, stream,
                       Whh1, Whh1_1, Whh1_2, 786432, 24);
    hipLaunchKernelGGL(preprocess_split_kernel, dim3(1024), dim3(256), 0, stream,
                       W1, W1_1, W1_2, 262144, 8);
    hipLaunchKernelGGL(rnn_wavefn_mfma_kernel, dim3(8192 / BTM), dim3(THM), 0, stream,
                       inputs, Wih0, bih0, bhh0, bih1, bhh1, b1, W2, b2,
                       Whh0_1, Whh0_2, Wih1_1, Wih1_2, Whh1_1, Whh1_2, W1_1, W1_2,
                       out);
  } else {
    hipLaunchKernelGGL(rnn_wavefn_fp32_kernel, dim3(8192 / BT), dim3(THREADS), 0, stream,
                       inputs, Wih0, Whh0, bih0, bhh0, Wih1, Whh1, bih1, bhh1,
                       W1, b1, W2, b2, out);
  }
}

// Round 8
// 3672.187 us; speedup vs baseline: 1.1144x; 1.1144x over previous
//
#include <hip/hip_runtime.h>
#include <cstdint>

// binary_disordered_RNNwavefunction: 128-step 2-layer GRU + MLP + softmax +
// threefry categorical sampling, B=8192, H=128, I=2.
//
// R8 = R7's fused-combine structure, DE-SPILLED. R7 regressed (4092 us) via
// scratch spill: VGPR capped at 128 because __launch_bounds__ 2nd arg is
// empirically min BLOCKS/CU (CUDA semantics; R5-R7 all report 124-128), and
// R7's carried gate registers pushed demand to ~210 -> 87 MB spill writes ->
// desync -> L2 thrash (FETCH 3.84 GB). Fixes:
//  - __launch_bounds__(512,1): 256-VGPR cap (LDS forces 1 block/CU anyway).
//  - No gates carried across barriers. P1 = GRU0 only (3 tiles + inline
//    combine). P2 = GRU1: r,z gates sum Whh1.h2 and Wih1.h1new IN the same
//    accumulators (A-sets loaded sequentially, registers reused); gh_n/gi_n
//    separate; inline GRU1+cos combine. P3 HDN, P4 OUT. 4 barriers.
//  - h1 AND h2 frag buffers ping-pong by parity (same-phase r/w hazard).
//
// Numerics (verified R4-R7, absmax 0.0039 floor): split-f16 a = a1+a2s/4096;
// 3 MFMAs/tile; dropped A2sB2s ~3e-8; bias/fold re-associations 1e-7 class.
// RNG (verified): modern JAX threefry_partitionable.
// R2: few lockstep blocks. R5: AI per B-load ~ BTM. R6: dbuf B prefetch.

namespace {

constexpr int NSTEPS = 128;
constexpr int HDIM = 128;
constexpr int G3H = 384;

constexpr int BTM = 32;        // batch rows per block
constexpr int THM = 512;       // threads (8 waves)

// fallback (R3) config
constexpr int BT = 16;
constexpr int THREADS = 256;
constexpr int HP = 132;
constexpr int SP = 516;

typedef _Float16 half8 __attribute__((ext_vector_type(8)));
typedef float f32x4 __attribute__((ext_vector_type(4)));

constexpr float LO_SCALE = 4096.0f;
constexpr float LO_INV = 2.44140625e-4f;   // 1/4096
constexpr float F16_MIN_NORM = 6.104e-5f;

__device__ __forceinline__ void split_f16(float x, _Float16& a1, _Float16& a2s) {
  _Float16 h = (fabsf(x) < F16_MIN_NORM) ? (_Float16)0.0f : (_Float16)x;
  a1 = h;
  a2s = (_Float16)((x - (float)h) * LO_SCALE);
}

__device__ __forceinline__ void tf2x32(uint32_t k0, uint32_t k1,
                                       uint32_t x0, uint32_t x1,
                                       uint32_t& o0, uint32_t& o1) {
  const uint32_t ks2 = k0 ^ k1 ^ 0x1BD11BDAu;
  uint32_t v0 = x0 + k0;
  uint32_t v1 = x1 + k1;
  const uint32_t ks[3] = {k0, k1, ks2};
  const uint32_t rotA[4] = {13u, 15u, 26u, 6u};
  const uint32_t rotB[4] = {17u, 29u, 16u, 24u};
#pragma unroll
  for (int i = 0; i < 5; ++i) {
#pragma unroll
    for (int j = 0; j < 4; ++j) {
      const uint32_t r = (i & 1) ? rotB[j] : rotA[j];
      v0 += v1;
      v1 = (v1 << r) | (v1 >> (32u - r));
      v1 ^= v0;
    }
    v0 += ks[(i + 1) % 3];
    v1 += ks[(i + 2) % 3] + (uint32_t)(i + 1);
  }
  o0 = v0;
  o1 = v1;
}

__device__ __forceinline__ float u01_from_bits(uint32_t bits) {
  const float tiny = 1.1754943508222875e-38f;
  float f = __uint_as_float((bits >> 9) | 0x3F800000u) - 1.0f;
  float u = f * (1.0f - tiny) + tiny;
  return fmaxf(tiny, u);
}

__device__ __forceinline__ float sigmoidf(float x) {
  return 1.0f / (1.0f + expf(-x));
}

__device__ __forceinline__ float dot4(const float4 a, const float4 b, float c) {
  c = fmaf(a.x, b.x, c);
  c = fmaf(a.y, b.y, c);
  c = fmaf(a.z, b.z, c);
  c = fmaf(a.w, b.w, c);
  return c;
}

__device__ __forceinline__ void load_Afrag(const _Float16* arr, int lane,
                                           half8 (&A)[2][4]) {
#pragma unroll
  for (int mt = 0; mt < 2; ++mt)
#pragma unroll
    for (int kt = 0; kt < 4; ++kt)
      A[mt][kt] = *(const half8*)(arr + mt * 2048 + (kt * 64 + lane) * 8);
}

__device__ __forceinline__ void load_B(const _Float16* __restrict__ B1,
                                       const _Float16* __restrict__ B2,
                                       int jt, int lane,
                                       half8 (&b1)[4], half8 (&b2)[4]) {
#pragma unroll
  for (int kt = 0; kt < 4; ++kt) {
    const size_t o = ((size_t)(jt * 4 + kt) * 64 + lane) * 8;
    b1[kt] = *(const half8*)(B1 + o);
    b2[kt] = *(const half8*)(B2 + o);
  }
}

__device__ __forceinline__ void mfma_regs(const half8 (&A1)[2][4],
                                          const half8 (&A2)[2][4],
                                          const half8 (&b1)[4],
                                          const half8 (&b2)[4],
                                          f32x4 (&c1)[2], f32x4 (&c2)[2]) {
#pragma unroll
  for (int kt = 0; kt < 4; ++kt)
#pragma unroll
    for (int mt = 0; mt < 2; ++mt) {
      c1[mt] = __builtin_amdgcn_mfma_f32_16x16x32_f16(A1[mt][kt], b1[kt], c1[mt], 0, 0, 0);
      c2[mt] = __builtin_amdgcn_mfma_f32_16x16x32_f16(A1[mt][kt], b2[kt], c2[mt], 0, 0, 0);
      c2[mt] = __builtin_amdgcn_mfma_f32_16x16x32_f16(A2[mt][kt], b1[kt], c2[mt], 0, 0, 0);
    }
}

__device__ __forceinline__ void zacc(f32x4 (&c)[2]) {
  c[0] = f32x4{0.f, 0.f, 0.f, 0.f};
  c[1] = f32x4{0.f, 0.f, 0.f, 0.f};
}

// g[mt][k] = bias + (c1 + c2/4096)
__device__ __forceinline__ void fold2(f32x4 (&g)[2], const f32x4 (&c1)[2],
                                      const f32x4 (&c2)[2], float bias) {
#pragma unroll
  for (int mt = 0; mt < 2; ++mt)
#pragma unroll
    for (int k = 0; k < 4; ++k)
      g[mt][k] = bias + fmaf(c2[mt][k], LO_INV, c1[mt][k]);
}

}  // namespace

// ---------------------------------------------------------------------------
// Preprocess: fp32 W[n][JT*16][128] -> frag-layout split-f16 arrays (as R4)
// ---------------------------------------------------------------------------
extern "C" __global__ __launch_bounds__(256)
void preprocess_split_kernel(const float* __restrict__ src,
                             _Float16* __restrict__ d1,
                             _Float16* __restrict__ d2,
                             int total, int JT) {
  const int idx = blockIdx.x * 256 + threadIdx.x;
  if (idx >= total) return;
  const int lane = idx & 63;
  const int kt = (idx >> 6) & 3;
  const int rest = idx >> 8;
  const int jt = rest % JT;
  const int nstep = rest / JT;

  const int j = jt * 16 + (lane & 15);
  const int k0 = kt * 32 + ((lane >> 4) << 3);
  const float* p = src + ((size_t)nstep * (JT * 16) + j) * 128 + k0;
  const float4 w0 = *(const float4*)p;
  const float4 w1 = *(const float4*)(p + 4);
  const float xs[8] = {w0.x, w0.y, w0.z, w0.w, w1.x, w1.y, w1.z, w1.w};

  half8 o1, o2;
#pragma unroll
  for (int t = 0; t < 8; ++t) {
    _Float16 a1, a2s;
    split_f16(xs[t], a1, a2s);
    o1[t] = a1;
    o2[t] = a2s;
  }
  *(half8*)(d1 + (size_t)idx * 8) = o1;
  *(half8*)(d2 + (size_t)idx * 8) = o2;
}

// ---------------------------------------------------------------------------
// Main MFMA kernel: BT=32, 512 threads, 1 block/CU, fused combines, no spill
// ---------------------------------------------------------------------------
extern "C" __global__ __launch_bounds__(512, 1)
void rnn_wavefn_mfma_kernel(const float* __restrict__ inputs,
                            const float* __restrict__ Wih0,
                            const float* __restrict__ bih0,
                            const float* __restrict__ bhh0,
                            const float* __restrict__ bih1,
                            const float* __restrict__ bhh1,
                            const float* __restrict__ b1,
                            const float* __restrict__ W2,
                            const float* __restrict__ b2,
                            const _Float16* __restrict__ Whh0_1,
                            const _Float16* __restrict__ Whh0_2,
                            const _Float16* __restrict__ Wih1_1,
                            const _Float16* __restrict__ Wih1_2,
                            const _Float16* __restrict__ Whh1_1,
                            const _Float16* __restrict__ Whh1_2,
                            const _Float16* __restrict__ W1_1,
                            const _Float16* __restrict__ W1_2,
                            float* __restrict__ out) {
  __shared__ _Float16 h1Aa1[4096], h1Aa2[4096];   // h1 frag ping
  __shared__ _Float16 h1Ab1[4096], h1Ab2[4096];   // h1 frag pong
  __shared__ _Float16 h2Aa1[4096], h2Aa2[4096];   // h2 frag ping
  __shared__ _Float16 h2Ab1[4096], h2Ab2[4096];   // h2 frag pong
  __shared__ _Float16 csA1[4096], csA2[4096];
  __shared__ float Shdn[BTM][132];
  __shared__ float xin[BTM][2];

  const int tid = threadIdx.x;
  const int b0 = blockIdx.x * BTM;
  const int wv = tid >> 6;        // 0..7
  const int lane = tid & 63;
  const int lm = lane & 15;
  const int m0 = (lane >> 4) * 4;
  const int col0 = wv * 16 + lm;  // this thread's gate column
  // A-frag write base for d=col0 (b16 elem index; add mt*2048 + (m0+q)*8)
  const int fw = (((col0 >> 5) * 64 + ((col0 >> 3) & 3) * 16) * 8) + (col0 & 7);

  float h1r[8], h2r[8];           // j = mt*4 + q  ->  b = mt*16 + m0 + q
#pragma unroll
  for (int i = 0; i < 8; ++i) { h1r[i] = 0.0f; h2r[i] = 0.0f; }
  for (int i = tid; i < 4096; i += THM) {
    h1Aa1[i] = (_Float16)0.0f; h1Aa2[i] = (_Float16)0.0f;
    h1Ab1[i] = (_Float16)0.0f; h1Ab2[i] = (_Float16)0.0f;
    h2Aa1[i] = (_Float16)0.0f; h2Aa2[i] = (_Float16)0.0f;
    h2Ab1[i] = (_Float16)0.0f; h2Ab2[i] = (_Float16)0.0f;
  }
  if (tid < BTM * 2) {
    xin[tid >> 1][tid & 1] = inputs[(b0 + (tid >> 1)) * 2 + (tid & 1)];
  }
  __syncthreads();

  for (int n = 0; n < NSTEPS; ++n) {
    const float* __restrict__ Wih0n = Wih0 + (size_t)n * G3H * 2;
    const float* __restrict__ bih0n = bih0 + (size_t)n * G3H;
    const float* __restrict__ bhh0n = bhh0 + (size_t)n * G3H;
    const float* __restrict__ bih1n = bih1 + (size_t)n * G3H;
    const float* __restrict__ bhh1n = bhh1 + (size_t)n * G3H;
    const float* __restrict__ b1n = b1 + (size_t)n * HDIM;
    const float* __restrict__ W2n = W2 + (size_t)n * 2 * HDIM;
    const float* __restrict__ b2n = b2 + (size_t)n * 2;
    const size_t fo3 = (size_t)n * 49152;
    const size_t fo1 = (size_t)n * 16384;

    // frag ping-pong (write = this step, read = prev step)
    _Float16* const h1W1 = (n & 1) ? h1Ab1 : h1Aa1;
    _Float16* const h1W2 = (n & 1) ? h1Ab2 : h1Aa2;
    const _Float16* const h1R1 = (n & 1) ? h1Aa1 : h1Ab1;
    const _Float16* const h1R2 = (n & 1) ? h1Aa2 : h1Ab2;
    _Float16* const h2W1 = (n & 1) ? h2Ab1 : h2Aa1;
    _Float16* const h2W2 = (n & 1) ? h2Ab2 : h2Aa2;
    const _Float16* const h2R1 = (n & 1) ? h2Aa1 : h2Ab1;
    const _Float16* const h2R2 = (n & 1) ? h2Aa2 : h2Ab2;

    // ---------- P1: GRU0 = 3 tiles (A = h1_prev) + inline combine -> h1
    {
      half8 A1[2][4], A2[2][4];
      load_Afrag(h1R1, lane, A1);
      load_Afrag(h1R2, lane, A2);
      const _Float16* Bh = Whh0_1 + fo3;
      const _Float16* Bl = Whh0_2 + fo3;
      half8 Pb1[2][4], Pb2[2][4];
      load_B(Bh, Bl, wv, lane, Pb1[0], Pb2[0]);

      f32x4 c1[2], c2[2], g0r[2], g0z[2], g0n[2];
      load_B(Bh, Bl, wv + 8, lane, Pb1[1], Pb2[1]);
      zacc(c1); zacc(c2);
      mfma_regs(A1, A2, Pb1[0], Pb2[0], c1, c2);
      fold2(g0r, c1, c2, bhh0n[col0]);
      load_B(Bh, Bl, wv + 16, lane, Pb1[0], Pb2[0]);
      zacc(c1); zacc(c2);
      mfma_regs(A1, A2, Pb1[1], Pb2[1], c1, c2);
      fold2(g0z, c1, c2, bhh0n[col0 + 128]);
      zacc(c1); zacc(c2);
      mfma_regs(A1, A2, Pb1[0], Pb2[0], c1, c2);
      fold2(g0n, c1, c2, bhh0n[col0 + 256]);

      const float wr0 = Wih0n[col0 * 2],         wr1 = Wih0n[col0 * 2 + 1];
      const float wz0 = Wih0n[(col0 + 128) * 2], wz1 = Wih0n[(col0 + 128) * 2 + 1];
      const float wn0 = Wih0n[(col0 + 256) * 2], wn1 = Wih0n[(col0 + 256) * 2 + 1];
      const float br = bih0n[col0];
      const float bz = bih0n[col0 + 128];
      const float bn = bih0n[col0 + 256];
#pragma unroll
      for (int j = 0; j < 8; ++j) {
        const int mt = j >> 2, q = j & 3;
        const int b = mt * 16 + m0 + q;
        const float x0 = xin[b][0], x1 = xin[b][1];
        const float gir = fmaf(wr0, x0, fmaf(wr1, x1, br));
        const float giz = fmaf(wz0, x0, fmaf(wz1, x1, bz));
        const float ginn = fmaf(wn0, x0, fmaf(wn1, x1, bn));
        const float rg = sigmoidf(gir + g0r[mt][q]);
        const float zg = sigmoidf(giz + g0z[mt][q]);
        const float ng = tanhf(ginn + rg * g0n[mt][q]);
        const float h1n = (1.0f - zg) * ng + zg * h1r[j];
        h1r[j] = h1n;
        _Float16 a1h, a2h;
        split_f16(h1n, a1h, a2h);
        const int off = fw + mt * 2048 + (m0 + q) * 8;
        h1W1[off] = a1h;
        h1W2[off] = a2h;
      }
    }
    __syncthreads();

    // ---------- P2: GRU1 = 6 tiles; r,z summed in-accumulator across the
    // two GEMMs (Whh1.h2_prev then Wih1.h1_new); gh_n/gi_n separate; inline
    // GRU1 combine + cos.
    {
      f32x4 cr1[2], cr2[2], cz1[2], cz2[2];
      f32x4 cnh1[2], cnh2[2], cni1[2], cni2[2];
      zacc(cr1); zacc(cr2); zacc(cz1); zacc(cz2);
      zacc(cnh1); zacc(cnh2); zacc(cni1); zacc(cni2);

      half8 A1[2][4], A2[2][4];
      half8 Pb1[2][4], Pb2[2][4];

      // pass 1: A = h2_prev, B = Whh1 tiles {wv, wv+8, wv+16}
      load_Afrag(h2R1, lane, A1);
      load_Afrag(h2R2, lane, A2);
      {
        const _Float16* Bh = Whh1_1 + fo3;
        const _Float16* Bl = Whh1_2 + fo3;
        load_B(Bh, Bl, wv, lane, Pb1[0], Pb2[0]);
        load_B(Bh, Bl, wv + 8, lane, Pb1[1], Pb2[1]);
        mfma_regs(A1, A2, Pb1[0], Pb2[0], cr1, cr2);
        load_B(Bh, Bl, wv + 16, lane, Pb1[0], Pb2[0]);
        mfma_regs(A1, A2, Pb1[1], Pb2[1], cz1, cz2);
        // prefetch first Wih1 tile into Pb[1]
        load_B(Wih1_1 + fo3, Wih1_2 + fo3, wv, lane, Pb1[1], Pb2[1]);
        mfma_regs(A1, A2, Pb1[0], Pb2[0], cnh1, cnh2);
      }
      // pass 2: A = h1_new, B = Wih1 tiles {wv, wv+8, wv+16}
      load_Afrag(h1W1, lane, A1);
      load_Afrag(h1W2, lane, A2);
      {
        const _Float16* Bh = Wih1_1 + fo3;
        const _Float16* Bl = Wih1_2 + fo3;
        load_B(Bh, Bl, wv + 8, lane, Pb1[0], Pb2[0]);
        mfma_regs(A1, A2, Pb1[1], Pb2[1], cr1, cr2);   // r: sum
        load_B(Bh, Bl, wv + 16, lane, Pb1[1], Pb2[1]);
        mfma_regs(A1, A2, Pb1[0], Pb2[0], cz1, cz2);   // z: sum
        mfma_regs(A1, A2, Pb1[1], Pb2[1], cni1, cni2); // gi_n: separate
      }

      const float brs = bhh1n[col0] + bih1n[col0];
      const float bzs = bhh1n[col0 + 128] + bih1n[col0 + 128];
      const float bnh = bhh1n[col0 + 256];
      const float bni = bih1n[col0 + 256];
#pragma unroll
      for (int j = 0; j < 8; ++j) {
        const int mt = j >> 2, q = j & 3;
        const float rg = sigmoidf(brs + fmaf(cr2[mt][q], LO_INV, cr1[mt][q]));
        const float zg = sigmoidf(bzs + fmaf(cz2[mt][q], LO_INV, cz1[mt][q]));
        const float ghn = bnh + fmaf(cnh2[mt][q], LO_INV, cnh1[mt][q]);
        const float gin = bni + fmaf(cni2[mt][q], LO_INV, cni1[mt][q]);
        const float ng = tanhf(gin + rg * ghn);
        const float h2n = (1.0f - zg) * ng + zg * h2r[j];
        h2r[j] = h2n;
        const int off = fw + mt * 2048 + (m0 + q) * 8;
        _Float16 a1h, a2h;
        split_f16(h2n, a1h, a2h);
        h2W1[off] = a1h;
        h2W2[off] = a2h;
        const float cv = cosf(h2n) + 1e-10f;
        split_f16(cv, a1h, a2h);
        csA1[off] = a1h;
        csA2[off] = a2h;
      }
    }
    __syncthreads();

    // ---------- P3: HDN = relu(b1 + W1 . cos)
    {
      half8 A1[2][4], A2[2][4];
      load_Afrag(csA1, lane, A1);
      load_Afrag(csA2, lane, A2);
      half8 b1v[4], b2v[4];
      load_B(W1_1 + fo1, W1_2 + fo1, wv, lane, b1v, b2v);
      f32x4 c1[2], c2[2];
      zacc(c1); zacc(c2);
      mfma_regs(A1, A2, b1v, b2v, c1, c2);
      const float bias = b1n[col0];
#pragma unroll
      for (int mt = 0; mt < 2; ++mt)
#pragma unroll
        for (int q = 0; q < 4; ++q)
          Shdn[mt * 16 + m0 + q][col0] =
              fmaxf(bias + fmaf(c2[mt][q], LO_INV, c1[mt][q]), 0.0f);
    }
    __syncthreads();

    // ---------- P4 OUT: logits, softmax+1e-10, store p, threefry-gumbel
    {
      const int ln = tid & 15;
      const int ob = tid >> 4;    // 0..31
      const int kb = ln * 8;
      float a0 = 0.0f, a1 = 0.0f;
#pragma unroll
      for (int k = 0; k < 8; ++k) {
        const float hd = Shdn[ob][kb + k];
        a0 = fmaf(W2n[kb + k], hd, a0);
        a1 = fmaf(W2n[HDIM + kb + k], hd, a1);
      }
#pragma unroll
      for (int off = 8; off >= 1; off >>= 1) {
        a0 += __shfl_xor(a0, off, 16);
        a1 += __shfl_xor(a1, off, 16);
      }
      if (ln == 0) {
        const float l0 = a0 + b2n[0];
        const float l1 = a1 + b2n[1];
        const float m = fmaxf(l0, l1);
        const float e0 = expf(l0 - m);
        const float e1 = expf(l1 - m);
        const float sum = e0 + e1;
        const float p0 = e0 / sum + 1e-10f;
        const float p1 = e1 / sum + 1e-10f;
        const int gb = b0 + ob;
        out[((size_t)gb * NSTEPS + n) * 2 + 0] = p0;
        out[((size_t)gb * NSTEPS + n) * 2 + 1] = p1;

        uint32_t k0n, k1n;
        tf2x32(0u, 42u, 0u, (uint32_t)n, k0n, k1n);
        uint32_t o0, o1;
        tf2x32(k0n, k1n, 0u, (uint32_t)(2 * gb), o0, o1);
        const float u0 = u01_from_bits(o0 ^ o1);
        tf2x32(k0n, k1n, 0u, (uint32_t)(2 * gb + 1), o0, o1);
        const float u1 = u01_from_bits(o0 ^ o1);
        const float g0 = -logf(-logf(u0));
        const float g1 = -logf(-logf(u1));
        const float z0 = logf(p0) + g0;
        const float z1 = logf(p1) + g1;
        const int smp = (z1 > z0) ? 1 : 0;
        xin[ob][0] = (smp == 0) ? 1.0f : 0.0f;
        xin[ob][1] = (smp == 1) ? 1.0f : 0.0f;
      }
    }
    __syncthreads();
  }
}

// ---------------------------------------------------------------------------
// Fallback: R3 fp32-VALU kernel (proven, 7.2 ms) — used if ws too small.
// ---------------------------------------------------------------------------
extern "C" __global__ __launch_bounds__(256, 2)
void rnn_wavefn_fp32_kernel(const float* __restrict__ inputs,
                            const float* __restrict__ Wih0,
                            const float* __restrict__ Whh0,
                            const float* __restrict__ bih0,
                            const float* __restrict__ bhh0,
                            const float* __restrict__ Wih1,
                            const float* __restrict__ Whh1,
                            const float* __restrict__ bih1,
                            const float* __restrict__ bhh1,
                            const float* __restrict__ W1,
                            const float* __restrict__ b1,
                            const float* __restrict__ W2,
                            const float* __restrict__ b2,
                            float* __restrict__ out) {
  __shared__ float h1[BT][HP];
  __shared__ float h2[BT][HP];
  __shared__ float S[BT][SP];
  __shared__ float xin[BT][2];

  const int tid = threadIdx.x;
  const int b0 = blockIdx.x * BT;
  const int tj = tid >> 2;
  const int tq = tid & 3;

  for (int i = tid; i < BT * HP; i += THREADS) {
    ((float*)h1)[i] = 0.0f;
    ((float*)h2)[i] = 0.0f;
  }
  if (tid < BT * 2) {
    xin[tid >> 1][tid & 1] = inputs[(b0 + (tid >> 1)) * 2 + (tid & 1)];
  }
  __syncthreads();

  for (int n = 0; n < NSTEPS; ++n) {
    const float* __restrict__ Wih0n = Wih0 + (size_t)n * G3H * 2;
    const float* __restrict__ Whh0n = Whh0 + (size_t)n * G3H * HDIM;
    const float* __restrict__ bih0n = bih0 + (size_t)n * G3H;
    const float* __restrict__ bhh0n = bhh0 + (size_t)n * G3H;
    const float* __restrict__ Wih1n = Wih1 + (size_t)n * G3H * HDIM;
    const float* __restrict__ Whh1n = Whh1 + (size_t)n * G3H * HDIM;
    const float* __restrict__ bih1n = bih1 + (size_t)n * G3H;
    const float* __restrict__ bhh1n = bhh1 + (size_t)n * G3H;
    const float* __restrict__ W1n = W1 + (size_t)n * HDIM * HDIM;
    const float* __restrict__ b1n = b1 + (size_t)n * HDIM;
    const float* __restrict__ W2n = W2 + (size_t)n * 2 * HDIM;
    const float* __restrict__ b2n = b2 + (size_t)n * 2;

    {
      float acc[6][4];
#pragma unroll
      for (int g = 0; g < 6; ++g) {
        const float bias = bhh0n[tj + g * 64];
#pragma unroll
        for (int i = 0; i < 4; ++i) acc[g][i] = bias;
      }
      for (int kk = 0; kk < HDIM; kk += 16) {
#pragma unroll
        for (int s = 0; s < 4; ++s) {
          const int k = kk + s * 4;
          float4 w[6];
#pragma unroll
          for (int g = 0; g < 6; ++g)
            w[g] = *(const float4*)(Whh0n + (size_t)(tj + g * 64) * HDIM + k);
#pragma unroll
          for (int i = 0; i < 4; ++i) {
            const float4 hv = *(const float4*)&h1[tq + 4 * i][k];
#pragma unroll
            for (int g = 0; g < 6; ++g) acc[g][i] = dot4(w[g], hv, acc[g][i]);
          }
        }
      }
#pragma unroll
      for (int g = 0; g < 6; ++g)
#pragma unroll
        for (int i = 0; i < 4; ++i) S[tq + 4 * i][tj + g * 64] = acc[g][i];
    }
    __syncthreads();

#pragma unroll
    for (int rep = 0; rep < (BT * HDIM) / THREADS; ++rep) {
      const int idx = tid + rep * THREADS;
      const int b = idx >> 7;
      const int d = idx & 127;
      const float x0 = xin[b][0];
      const float x1 = xin[b][1];
      const float gir = fmaf(Wih0n[d * 2 + 0], x0, fmaf(Wih0n[d * 2 + 1], x1, bih0n[d]));
      const float giz = fmaf(Wih0n[(d + 128) * 2 + 0], x0,
                             fmaf(Wih0n[(d + 128) * 2 + 1], x1, bih0n[d + 128]));
      const float gin = fmaf(Wih0n[(d + 256) * 2 + 0], x0,
                             fmaf(Wih0n[(d + 256) * 2 + 1], x1, bih0n[d + 256]));
      const float r = sigmoidf(gir + S[b][d]);
      const float z = sigmoidf(giz + S[b][d + 128]);
      const float nn = tanhf(gin + r * S[b][d + 256]);
      h1[b][d] = (1.0f - z) * nn + z * h1[b][d];
    }
    __syncthreads();

    {
      float acc[6][4];
#pragma unroll
      for (int g = 0; g < 6; ++g) {
        const float bias = bhh1n[tj + g * 64];
#pragma unroll
        for (int i = 0; i < 4; ++i) acc[g][i] = bias;
      }
      for (int kk = 0; kk < HDIM; kk += 16) {
#pragma unroll
        for (int s = 0; s < 4; ++s) {
          const int k = kk + s * 4;
          float4 w[6];
#pragma unroll
          for (int g = 0; g < 6; ++g)
            w[g] = *(const float4*)(Whh1n + (size_t)(tj + g * 64) * HDIM + k);
#pragma unroll
          for (int i = 0; i < 4; ++i) {
            const float4 hv = *(const float4*)&h2[tq + 4 * i][k];
#pragma unroll
            for (int g = 0; g < 6; ++g) acc[g][i] = dot4(w[g], hv, acc[g][i]);
          }
        }
      }
#pragma unroll
      for (int g = 0; g < 6; ++g)
#pragma unroll
        for (int i = 0; i < 4; ++i) S[tq + 4 * i][tj + g * 64] = acc[g][i];
    }

    {
      float acc[6][4];
#pragma unroll
      for (int g = 0; g < 6; ++g) {
        const float bias = bih1n[tj + g * 64];
#pragma unroll
        for (int i = 0; i < 4; ++i) acc[g][i] = bias;
      }
      for (int kk = 0; kk < HDIM; kk += 16) {
#pragma unroll
        for (int s = 0; s < 4; ++s) {
          const int k = kk + s * 4;
          float4 w[6];
#pragma unroll
          for (int g = 0; g < 6; ++g)
            w[g] = *(const float4*)(Wih1n + (size_t)(tj + g * 64) * HDIM + k);
#pragma unroll
          for (int i = 0; i < 4; ++i) {
            const float4 hv = *(const float4*)&h1[tq + 4 * i][k];
#pragma unroll
            for (int g = 0; g < 6; ++g) acc[g][i] = dot4(w[g], hv, acc[g][i]);
          }
        }
      }
#pragma unroll
      for (int g = 0; g < 6; ++g) {
        const int row = tj + g * 64;
#pragma unroll
        for (int i = 0; i < 4; ++i) {
          if (row < 256) S[tq + 4 * i][row] += acc[g][i];
          else           S[tq + 4 * i][row + 128] = acc[g][i];
        }
      }
    }
    __syncthreads();

#pragma unroll
    for (int rep = 0; rep < (BT * HDIM) / THREADS; ++rep) {
      const int idx = tid + rep * THREADS;
      const int b = idx >> 7;
      const int d = idx & 127;
      const float r = sigmoidf(S[b][d]);
      const float z = sigmoidf(S[b][d + 128]);
      const float nn = tanhf(S[b][d + 384] + r * S[b][d + 256]);
      const float h2n = (1.0f - z) * nn + z * h2[b][d];
      h2[b][d] = h2n;
      S[b][d] = cosf(h2n) + 1e-10f;
    }
    __syncthreads();

    {
      float acc[2][4];
#pragma unroll
      for (int g = 0; g < 2; ++g) {
        const float bias = b1n[tj + g * 64];
#pragma unroll
        for (int i = 0; i < 4; ++i) acc[g][i] = bias;
      }
      for (int kk = 0; kk < HDIM; kk += 16) {
#pragma unroll
        for (int s = 0; s < 4; ++s) {
          const int k = kk + s * 4;
          float4 w[2];
          w[0] = *(const float4*)(W1n + (size_t)(tj)*HDIM + k);
          w[1] = *(const float4*)(W1n + (size_t)(tj + 64) * HDIM + k);
#pragma unroll
          for (int i = 0; i < 4; ++i) {
            const float4 sv = *(const float4*)&S[tq + 4 * i][k];
            acc[0][i] = dot4(w[0], sv, acc[0][i]);
            acc[1][i] = dot4(w[1], sv, acc[1][i]);
          }
        }
      }
#pragma unroll
      for (int g = 0; g < 2; ++g)
#pragma unroll
        for (int i = 0; i < 4; ++i)
          S[tq + 4 * i][384 + tj + g * 64] = fmaxf(acc[g][i], 0.0f);
    }
    __syncthreads();

    {
      const int ln = tid & 15;
      const int b = tid >> 4;
      const int kb = ln * 8;
      float a0 = 0.0f, a1 = 0.0f;
#pragma unroll
      for (int k = 0; k < 8; ++k) {
        const float hd = S[b][384 + kb + k];
        a0 = fmaf(W2n[kb + k], hd, a0);
        a1 = fmaf(W2n[HDIM + kb + k], hd, a1);
      }
#pragma unroll
      for (int off = 8; off >= 1; off >>= 1) {
        a0 += __shfl_xor(a0, off, 16);
        a1 += __shfl_xor(a1, off, 16);
      }
      if (ln == 0) {
        const float l0 = a0 + b2n[0];
        const float l1 = a1 + b2n[1];
        const float m = fmaxf(l0, l1);
        const float e0 = expf(l0 - m);
        const float e1 = expf(l1 - m);
        const float sum = e0 + e1;
        const float p0 = e0 / sum + 1e-10f;
        const float p1 = e1 / sum + 1e-10f;
        const int gb = b0 + b;
        out[((size_t)gb * NSTEPS + n) * 2 + 0] = p0;
        out[((size_t)gb * NSTEPS + n) * 2 + 1] = p1;

        uint32_t k0n, k1n;
        tf2x32(0u, 42u, 0u, (uint32_t)n, k0n, k1n);
        uint32_t o0, o1;
        tf2x32(k0n, k1n, 0u, (uint32_t)(2 * gb), o0, o1);
        const float u0 = u01_from_bits(o0 ^ o1);
        tf2x32(k0n, k1n, 0u, (uint32_t)(2 * gb + 1), o0, o1);
        const float u1 = u01_from_bits(o0 ^ o1);
        const float g0 = -logf(-logf(u0));
        const float g1 = -logf(-logf(u1));
        const float z0 = logf(p0) + g0;
        const float z1 = logf(p1) + g1;
        const int smp = (z1 > z0) ? 1 : 0;
        xin[b][0] = (smp == 0) ? 1.0f : 0.0f;
        xin[b][1] = (smp == 1) ? 1.0f : 0.0f;
      }
    }
    __syncthreads();
  }
}

extern "C" void kernel_launch(void* const* d_in, const int* in_sizes, int n_in,
                              void* d_out, int out_size, void* d_ws, size_t ws_size,
                              hipStream_t stream) {
  (void)in_sizes; (void)n_in; (void)out_size;
  const float* inputs = (const float*)d_in[0];
  const float* Wih0 = (const float*)d_in[1];
  const float* Whh0 = (const float*)d_in[2];
  const float* bih0 = (const float*)d_in[3];
  const float* bhh0 = (const float*)d_in[4];
  const float* Wih1 = (const float*)d_in[5];
  const float* Whh1 = (const float*)d_in[6];
  const float* bih1 = (const float*)d_in[7];
  const float* bhh1 = (const float*)d_in[8];
  const float* W1 = (const float*)d_in[9];
  const float* b1 = (const float*)d_in[10];
  const float* W2 = (const float*)d_in[11];
  const float* b2 = (const float*)d_in[12];
  float* out = (float*)d_out;

  constexpr size_t EB = 6291456;        // 128*24*4*64*8
  constexpr size_t EW1 = 2097152;       // 128*8*4*64*8
  constexpr size_t WS_NEEDED = (6 * EB + 2 * EW1) * sizeof(_Float16);

  if (ws_size >= WS_NEEDED) {
    _Float16* w = (_Float16*)d_ws;
    _Float16* Whh0_1 = w;
    _Float16* Whh0_2 = w + EB;
    _Float16* Wih1_1 = w + 2 * EB;
    _Float16* Wih1_2 = w + 3 * EB;
    _Float16* Whh1_1 = w + 4 * EB;
    _Float16* Whh1_2 = w + 5 * EB;
    _Float16* W1_1 = w + 6 * EB;
    _Float16* W1_2 = w + 6 * EB + EW1;

    hipLaunchKernelGGL(preprocess_split_kernel, dim3(3072), dim3(256), 0, stream,
                       Whh0, Whh0_1, Whh0_2, 786432, 24);
    hipLaunchKernelGGL(preprocess_split_kernel, dim3(3072), dim3(256), 0, stream,
                       Wih1, Wih1_1, Wih1_2, 786432, 24);
    hipLaunchKernelGGL(preprocess_split_kernel, dim3(3072), dim3(256), 0, stream,
                       Whh1, Whh1_1, Whh1_2, 786432, 24);
    hipLaunchKernelGGL(preprocess_split_kernel, dim3(1024), dim3(256), 0, stream,
                       W1, W1_1, W1_2, 262144, 8);
    hipLaunchKernelGGL(rnn_wavefn_mfma_kernel, dim3(8192 / BTM), dim3(THM), 0, stream,
                       inputs, Wih0, bih0, bhh0, bih1, bhh1, b1, W2, b2,
                       Whh0_1, Whh0_2, Wih1_1, Wih1_2, Whh1_1, Whh1_2, W1_1, W1_2,
                       out);
  } else {
    hipLaunchKernelGGL(rnn_wavefn_fp32_kernel, dim3(8192 / BT), dim3(THREADS), 0, stream,
                       inputs, Wih0, Whh0, bih0, bhh0, Wih1, Whh1, bih1, bhh1,
                       W1, b1, W2, b2, out);
  }
}